// Round 1
// baseline (856.032 us; speedup 1.0000x reference)
//
#include <hip/hip_runtime.h>
#include <stdint.h>

#define H 512
#define W 512
#define HW (H * W)
#define NIMG 128
#define AX 26214
#define NB 8192
#define CAND_CAP 7168
#define RR 2

// Edge magnitude, identical expression in both kernels (bitwise-consistent
// so threshold comparisons agree with the selection pass).
__device__ __forceinline__ float edge_mag(const float* __restrict__ x, int r, int c) {
  float a00 = x[r * W + c];
  float a01 = (c + 1 < W) ? x[r * W + c + 1] : 0.0f;
  float a10 = (r + 1 < H) ? x[(r + 1) * W + c] : 0.0f;
  float a11 = (r + 1 < H && c + 1 < W) ? x[(r + 1) * W + c + 1] : 0.0f;
  float g0 = a00 - a11;  // kx = [[1,0],[0,-1]]
  float g1 = a01 - a10;  // ky = [[0,1],[-1,0]]
  return sqrtf(fmaf(g0, g0, fmaf(g1, g1, 1e-12f)));
}

// Find bin b such that suffix_excl(b) < K <= suffix_excl(b) + hist[b],
// i.e. the bin holding the K-th largest element. Writes chosen bin and the
// remaining rank (from the top, 1-indexed) within that bin.
// Block = 512 threads; hist has NB=8192 bins.
__device__ __forceinline__ void block_select(uint32_t* hist, uint32_t* chunkSuf,
                                             uint32_t* outBin, uint32_t* outRank,
                                             uint32_t K) {
  int tid = threadIdx.x;
  int base = tid * 16;
  uint32_t csum = 0;
#pragma unroll
  for (int k = 0; k < 16; k++) csum += hist[base + k];
  chunkSuf[tid] = csum;  // chunk sums (512 chunks x 16 bins)
  __syncthreads();
  if (tid < 64) {
    uint32_t cs[8];
    uint32_t g = 0;
#pragma unroll
    for (int m = 0; m < 8; m++) { cs[m] = chunkSuf[tid * 8 + m]; g += cs[m]; }
    // inclusive suffix scan across 64 lanes
    uint32_t v = g;
#pragma unroll
    for (int off = 1; off < 64; off <<= 1) {
      uint32_t u = __shfl_down(v, off);
      if (tid + off < 64) v += u;
    }
    uint32_t run = v - g;  // sum over lanes > tid
    for (int m = 7; m >= 0; m--) {
      chunkSuf[tid * 8 + m] = run;  // suffix-exclusive per chunk
      run += cs[m];
    }
  }
  __syncthreads();
  uint32_t run = chunkSuf[tid];
  for (int k = 15; k >= 0; k--) {
    uint32_t h = hist[base + k];
    if (run < K && run + h >= K) {
      *outBin = (uint32_t)(base + k);
      *outRank = K - run;
    }
    run += h;
  }
  __syncthreads();
}

// One block per (tensor, image): exact rank-AX threshold via radix select on
// float bits (all mags > 0, so uint order == float order).
__global__ __launch_bounds__(512) void selectKernel(const float* __restrict__ target,
                                                    const float* __restrict__ pred,
                                                    float* __restrict__ thr) {
  __shared__ uint32_t hist[NB];
  __shared__ uint32_t cand[CAND_CAP];
  __shared__ uint32_t chunkSuf[512];
  __shared__ uint32_t sBin, sRank, sCnt;
  int tid = threadIdx.x;
  int b = blockIdx.x;
  int img = b & 127;
  const float* __restrict__ x = ((b >> 7) ? pred : target) + (size_t)img * HW;

  for (int i = tid; i < NB; i += 512) hist[i] = 0;
  if (tid == 0) { sBin = 0; sRank = 1; sCnt = 0; }
  __syncthreads();

  // Pass A: 13-bit-prefix histogram (one row per iteration; L1 catches reuse)
#pragma unroll 2
  for (int it = 0; it < HW / 512; ++it) {
    uint32_t bits = __float_as_uint(edge_mag(x, it, tid));
    atomicAdd(&hist[bits >> 19], 1u);
  }
  __syncthreads();
  block_select(hist, chunkSuf, &sBin, &sRank, AX);
  uint32_t b0 = sBin;
  uint32_t K1 = sRank;
  __syncthreads();

  // Pass B: compact candidates with matching 13-bit prefix into LDS
#pragma unroll 2
  for (int it = 0; it < HW / 512; ++it) {
    uint32_t bits = __float_as_uint(edge_mag(x, it, tid));
    if ((bits >> 19) == b0) {
      uint32_t idx = atomicAdd(&sCnt, 1u);
      if (idx < CAND_CAP) cand[idx] = bits;
    }
  }
  __syncthreads();
  uint32_t cnt = sCnt;
  if (cnt > CAND_CAP) cnt = CAND_CAP;  // ~4.9K expected; cap is >30 sigma away

  // Mini-round 1: next 13 bits, in-LDS
  for (int i = tid; i < NB; i += 512) hist[i] = 0;
  __syncthreads();
  for (uint32_t j = tid; j < cnt; j += 512)
    atomicAdd(&hist[(cand[j] >> 6) & 0x1FFFu], 1u);
  __syncthreads();
  block_select(hist, chunkSuf, &sBin, &sRank, K1);
  uint32_t b1 = sBin;
  uint32_t K2 = sRank;
  __syncthreads();

  // Mini-round 2: last 6 bits
  for (int i = tid; i < NB; i += 512) hist[i] = 0;
  __syncthreads();
  for (uint32_t j = tid; j < cnt; j += 512) {
    uint32_t bits = cand[j];
    if (((bits >> 6) & 0x1FFFu) == b1) atomicAdd(&hist[bits & 63u], 1u);
  }
  __syncthreads();
  block_select(hist, chunkSuf, &sBin, &sRank, K2);
  if (tid == 0) {
    uint32_t tb = (b0 << 19) | (b1 << 6) | sBin;
    thr[b] = __uint_as_float(tb);  // [0..127]=target, [128..255]=pred
  }
}

// Per-position sequential carry over the 128 images. Each thread owns RR
// vertically-adjacent positions in one column; loads RR+1 rows per tensor.
__global__ __launch_bounds__(256) void scanKernel(const float* __restrict__ target,
                                                  const float* __restrict__ pred,
                                                  const float* __restrict__ thr,
                                                  double* __restrict__ sum) {
  __shared__ float sT[NIMG], sP[NIMG];
  int tid = threadIdx.x;
  if (tid < NIMG) { sT[tid] = thr[tid]; sP[tid] = thr[NIMG + tid]; }
  __syncthreads();
  int c = blockIdx.x * 256 + tid;
  int r0 = blockIdx.y * RR;
  const bool lastCol = (c == W - 1);
  const bool lastRow = (r0 + RR == H);
  size_t base = (size_t)r0 * W + c;
  float etf[RR], epf[RR];
#pragma unroll
  for (int k = 0; k < RR; k++) { etf[k] = 0.0f; epf[k] = 0.0f; }
  float acc = 0.0f;
  for (int i = 0; i < NIMG; i++) {
    const float* xt = target + (size_t)i * HW + base;
    const float* xp = pred + (size_t)i * HW + base;
    float aT[RR + 1], bT[RR + 1], aP[RR + 1], bP[RR + 1];
#pragma unroll
    for (int k = 0; k <= RR; k++) {
      bool rowOk = (k < RR) || !lastRow;
      aT[k] = rowOk ? xt[k * W] : 0.0f;
      bT[k] = (rowOk && !lastCol) ? xt[k * W + 1] : 0.0f;
      aP[k] = rowOk ? xp[k * W] : 0.0f;
      bP[k] = (rowOk && !lastCol) ? xp[k * W + 1] : 0.0f;
    }
    float tT = sT[i], tP = sP[i];
#pragma unroll
    for (int k = 0; k < RR; k++) {
      float g0 = aT[k] - bT[k + 1];
      float g1 = bT[k] - aT[k + 1];
      float mT = sqrtf(fmaf(g0, g0, fmaf(g1, g1, 1e-12f)));
      if (mT >= tT) etf[k] = mT;
      g0 = aP[k] - bP[k + 1];
      g1 = bP[k] - aP[k + 1];
      float mP = sqrtf(fmaf(g0, g0, fmaf(g1, g1, 1e-12f)));
      if (mP >= tP) epf[k] = mP;
      acc += fabsf((etf[k] - epf[k]) / (etf[k] + epf[k] + 1e-5f));
    }
  }
  // block reduction -> f64 atomic
  for (int off = 32; off; off >>= 1) acc += __shfl_down(acc, off);
  __shared__ float ws4[4];
  if ((tid & 63) == 0) ws4[tid >> 6] = acc;
  __syncthreads();
  if (tid == 0) {
    double s = (double)ws4[0] + (double)ws4[1] + (double)ws4[2] + (double)ws4[3];
    atomicAdd(sum, s);
  }
}

__global__ void initKernel(double* __restrict__ sum) { *sum = 0.0; }

__global__ void finalKernel(const double* __restrict__ sum,
                            const float* __restrict__ alpha,
                            float* __restrict__ out) {
  out[0] = (float)((double)alpha[0] * (sum[0] / (double)((double)NIMG * (double)HW)));
}

extern "C" void kernel_launch(void* const* d_in, const int* in_sizes, int n_in,
                              void* d_out, int out_size, void* d_ws, size_t ws_size,
                              hipStream_t stream) {
  const float* pred = (const float*)d_in[0];    // predictions [16,8,512,512]
  const float* target = (const float*)d_in[1];  // target      [16,8,512,512]
  const float* alpha = (const float*)d_in[2];   // scalar
  // d_in[3] = Roberts kernels (fixed values, hardcoded in edge_mag)

  double* d_sum = (double*)d_ws;
  float* d_thr = (float*)((char*)d_ws + 64);  // 256 floats

  initKernel<<<1, 1, 0, stream>>>(d_sum);
  selectKernel<<<256, 512, 0, stream>>>(target, pred, d_thr);
  scanKernel<<<dim3(W / 256, H / RR), 256, 0, stream>>>(target, pred, d_thr, d_sum);
  finalKernel<<<1, 1, 0, stream>>>(d_sum, alpha, (float*)d_out);
}

// Round 2
// 528.540 us; speedup vs baseline: 1.6196x; 1.6196x over previous
//
#include <hip/hip_runtime.h>
#include <stdint.h>

#define H 512
#define W 512
#define HW (H * W)
#define NIMG 128
#define AX 26214
#define NB 8192
#define CAND_CAP 7168

// Find bin b such that suffix_excl(b) < K <= suffix_excl(b) + hist[b],
// i.e. the bin holding the K-th largest element. Writes chosen bin and the
// remaining rank (from the top, 1-indexed) within that bin.
// Block = 512 threads; hist has NB=8192 bins.
__device__ __forceinline__ void block_select(uint32_t* hist, uint32_t* chunkSuf,
                                             uint32_t* outBin, uint32_t* outRank,
                                             uint32_t K) {
  int tid = threadIdx.x;
  int base = tid * 16;
  uint32_t csum = 0;
#pragma unroll
  for (int k = 0; k < 16; k++) csum += hist[base + k];
  chunkSuf[tid] = csum;  // chunk sums (512 chunks x 16 bins)
  __syncthreads();
  if (tid < 64) {
    uint32_t cs[8];
    uint32_t g = 0;
#pragma unroll
    for (int m = 0; m < 8; m++) { cs[m] = chunkSuf[tid * 8 + m]; g += cs[m]; }
    // inclusive suffix scan across 64 lanes
    uint32_t v = g;
#pragma unroll
    for (int off = 1; off < 64; off <<= 1) {
      uint32_t u = __shfl_down(v, off);
      if (tid + off < 64) v += u;
    }
    uint32_t run = v - g;  // sum over lanes > tid
    for (int m = 7; m >= 0; m--) {
      chunkSuf[tid * 8 + m] = run;  // suffix-exclusive per chunk
      run += cs[m];
    }
  }
  __syncthreads();
  uint32_t run = chunkSuf[tid];
  for (int k = 15; k >= 0; k--) {
    uint32_t h = hist[base + k];
    if (run < K && run + h >= K) {
      *outBin = (uint32_t)(base + k);
      *outRank = K - run;
    }
    run += h;
  }
  __syncthreads();
}

// One block per (tensor, image): exact rank-AX threshold via radix select on
// float bits (all mags > 0, so uint order == float order).
// Each thread owns 4 consecutive columns (float4 loads) -> 4x MLP vs scalar.
__global__ __launch_bounds__(512) void selectKernel(const float* __restrict__ target,
                                                    const float* __restrict__ pred,
                                                    float* __restrict__ thr) {
  __shared__ uint32_t hist[NB];        // 32 KB
  __shared__ uint32_t cand[CAND_CAP];  // 28 KB
  __shared__ uint32_t chunkSuf[512];   // 2 KB
  __shared__ uint32_t sBin, sRank, sCnt;
  int tid = threadIdx.x;
  int b = blockIdx.x;
  int img = b & 127;
  const float* __restrict__ x = ((b >> 7) ? pred : target) + (size_t)img * HW;

  for (int i = tid; i < NB; i += 512) hist[i] = 0;
  if (tid == 0) { sBin = 0; sRank = 1; sCnt = 0; }
  __syncthreads();

  const int lane_c = (tid & 127) << 2;  // column base (multiple of 4)
  const int row_off = tid >> 7;         // 0..3 (wave-uniform)
  const bool haveE = (lane_c + 4 < W);

  // Pass A: 13-bit-prefix histogram
#pragma unroll 2
  for (int it = 0; it < H / 4; ++it) {
    int r = it * 4 + row_off;
    const float* rowp = x + r * W + lane_c;
    float4 v0 = *(const float4*)rowp;
    float e0 = haveE ? rowp[4] : 0.0f;
    float4 v1;
    float e1;
    if (r + 1 < H) {
      v1 = *(const float4*)(rowp + W);
      e1 = haveE ? rowp[W + 4] : 0.0f;
    } else {
      v1 = make_float4(0.f, 0.f, 0.f, 0.f);
      e1 = 0.0f;
    }
    float a0[5] = {v0.x, v0.y, v0.z, v0.w, e0};
    float a1[5] = {v1.x, v1.y, v1.z, v1.w, e1};
#pragma unroll
    for (int j = 0; j < 4; j++) {
      float g0 = a0[j] - a1[j + 1];
      float g1 = a0[j + 1] - a1[j];
      float m = sqrtf(fmaf(g0, g0, fmaf(g1, g1, 1e-12f)));
      atomicAdd(&hist[__float_as_uint(m) >> 19], 1u);
    }
  }
  __syncthreads();
  block_select(hist, chunkSuf, &sBin, &sRank, AX);
  uint32_t b0 = sBin;
  uint32_t K1 = sRank;
  __syncthreads();

  // Pass B: compact candidates with matching 13-bit prefix into LDS
#pragma unroll 2
  for (int it = 0; it < H / 4; ++it) {
    int r = it * 4 + row_off;
    const float* rowp = x + r * W + lane_c;
    float4 v0 = *(const float4*)rowp;
    float e0 = haveE ? rowp[4] : 0.0f;
    float4 v1;
    float e1;
    if (r + 1 < H) {
      v1 = *(const float4*)(rowp + W);
      e1 = haveE ? rowp[W + 4] : 0.0f;
    } else {
      v1 = make_float4(0.f, 0.f, 0.f, 0.f);
      e1 = 0.0f;
    }
    float a0[5] = {v0.x, v0.y, v0.z, v0.w, e0};
    float a1[5] = {v1.x, v1.y, v1.z, v1.w, e1};
#pragma unroll
    for (int j = 0; j < 4; j++) {
      float g0 = a0[j] - a1[j + 1];
      float g1 = a0[j + 1] - a1[j];
      float m = sqrtf(fmaf(g0, g0, fmaf(g1, g1, 1e-12f)));
      uint32_t bits = __float_as_uint(m);
      if ((bits >> 19) == b0) {
        uint32_t idx = atomicAdd(&sCnt, 1u);
        if (idx < CAND_CAP) cand[idx] = bits;
      }
    }
  }
  __syncthreads();
  uint32_t cnt = sCnt;
  if (cnt > CAND_CAP) cnt = CAND_CAP;  // ~5K expected; cap is far in the tail

  // Mini-round 1: next 13 bits, in-LDS
  for (int i = tid; i < NB; i += 512) hist[i] = 0;
  __syncthreads();
  for (uint32_t j = tid; j < cnt; j += 512)
    atomicAdd(&hist[(cand[j] >> 6) & 0x1FFFu], 1u);
  __syncthreads();
  block_select(hist, chunkSuf, &sBin, &sRank, K1);
  uint32_t b1 = sBin;
  uint32_t K2 = sRank;
  __syncthreads();

  // Mini-round 2: last 6 bits
  for (int i = tid; i < NB; i += 512) hist[i] = 0;
  __syncthreads();
  for (uint32_t j = tid; j < cnt; j += 512) {
    uint32_t bits = cand[j];
    if (((bits >> 6) & 0x1FFFu) == b1) atomicAdd(&hist[bits & 63u], 1u);
  }
  __syncthreads();
  block_select(hist, chunkSuf, &sBin, &sRank, K2);
  if (tid == 0) {
    uint32_t tb = (b0 << 19) | (b1 << 6) | sBin;
    thr[b] = __uint_as_float(tb);  // [0..127]=target, [128..255]=pred
  }
}

// Per-position sequential carry over the 128 images. Each thread owns 2
// vertically-adjacent positions in one column; software-pipelined: image
// i+1's 12 loads are issued before computing image i.
__global__ __launch_bounds__(256) void scanKernel(const float* __restrict__ target,
                                                  const float* __restrict__ pred,
                                                  const float* __restrict__ thr,
                                                  double* __restrict__ sum) {
  __shared__ float sT[NIMG], sP[NIMG];
  int tid = threadIdx.x;
  if (tid < NIMG) { sT[tid] = thr[tid]; sP[tid] = thr[NIMG + tid]; }
  __syncthreads();
  int c = blockIdx.x * 256 + tid;
  int r0 = blockIdx.y * 2;
  const bool lastCol = (c == W - 1);
  const bool lastRow = (r0 + 2 == H);
  size_t base = (size_t)r0 * W + c;

  float aT[2][3], bT[2][3], aP[2][3], bP[2][3];

#define LOADIMG(i, buf)                                              \
  {                                                                  \
    const float* xt = target + (size_t)(i) * HW + base;              \
    const float* xp = pred + (size_t)(i) * HW + base;                \
    _Pragma("unroll") for (int k = 0; k < 3; k++) {                  \
      bool rowOk = (k < 2) || !lastRow;                              \
      aT[buf][k] = rowOk ? xt[k * W] : 0.0f;                         \
      bT[buf][k] = (rowOk && !lastCol) ? xt[k * W + 1] : 0.0f;       \
      aP[buf][k] = rowOk ? xp[k * W] : 0.0f;                         \
      bP[buf][k] = (rowOk && !lastCol) ? xp[k * W + 1] : 0.0f;       \
    }                                                                \
  }

  LOADIMG(0, 0)

  float etf[2] = {0.0f, 0.0f}, epf[2] = {0.0f, 0.0f};
  float acc = 0.0f;
#pragma unroll 2
  for (int i = 0; i < NIMG; i++) {
    int cb = i & 1;
    if (i + 1 < NIMG) LOADIMG(i + 1, cb ^ 1)
    float tT = sT[i], tP = sP[i];
#pragma unroll
    for (int k = 0; k < 2; k++) {
      float g0 = aT[cb][k] - bT[cb][k + 1];
      float g1 = bT[cb][k] - aT[cb][k + 1];
      float mT = sqrtf(fmaf(g0, g0, fmaf(g1, g1, 1e-12f)));
      if (mT >= tT) etf[k] = mT;
      g0 = aP[cb][k] - bP[cb][k + 1];
      g1 = bP[cb][k] - aP[cb][k + 1];
      float mP = sqrtf(fmaf(g0, g0, fmaf(g1, g1, 1e-12f)));
      if (mP >= tP) epf[k] = mP;
      acc += fabsf((etf[k] - epf[k]) / (etf[k] + epf[k] + 1e-5f));
    }
  }
#undef LOADIMG

  // block reduction -> f64 atomic
  for (int off = 32; off; off >>= 1) acc += __shfl_down(acc, off);
  __shared__ float ws4[4];
  if ((tid & 63) == 0) ws4[tid >> 6] = acc;
  __syncthreads();
  if (tid == 0) {
    double s = (double)ws4[0] + (double)ws4[1] + (double)ws4[2] + (double)ws4[3];
    atomicAdd(sum, s);
  }
}

__global__ void initKernel(double* __restrict__ sum) { *sum = 0.0; }

__global__ void finalKernel(const double* __restrict__ sum,
                            const float* __restrict__ alpha,
                            float* __restrict__ out) {
  out[0] = (float)((double)alpha[0] * (sum[0] / (double)((double)NIMG * (double)HW)));
}

extern "C" void kernel_launch(void* const* d_in, const int* in_sizes, int n_in,
                              void* d_out, int out_size, void* d_ws, size_t ws_size,
                              hipStream_t stream) {
  const float* pred = (const float*)d_in[0];    // predictions [16,8,512,512]
  const float* target = (const float*)d_in[1];  // target      [16,8,512,512]
  const float* alpha = (const float*)d_in[2];   // scalar
  // d_in[3] = Roberts kernels (fixed values, hardcoded in edge computation)

  double* d_sum = (double*)d_ws;
  float* d_thr = (float*)((char*)d_ws + 64);  // 256 floats

  initKernel<<<1, 1, 0, stream>>>(d_sum);
  selectKernel<<<256, 512, 0, stream>>>(target, pred, d_thr);
  scanKernel<<<dim3(W / 256, H / 2), 256, 0, stream>>>(target, pred, d_thr, d_sum);
  finalKernel<<<1, 1, 0, stream>>>(d_sum, alpha, (float*)d_out);
}

// Round 3
// 524.344 us; speedup vs baseline: 1.6326x; 1.0080x over previous
//
#include <hip/hip_runtime.h>
#include <stdint.h>

#define H 512
#define W 512
#define HW (H * W)
#define NIMG 128
#define AX 26214
#define NB 8192
#define CAND_CAP 7168

__device__ __forceinline__ float4 f4zero() { return make_float4(0.f, 0.f, 0.f, 0.f); }

// Find bin b such that suffix_excl(b) < K <= suffix_excl(b) + hist[b].
// Block = 512 threads; hist has NB=8192 bins.
__device__ __forceinline__ void block_select(uint32_t* hist, uint32_t* chunkSuf,
                                             uint32_t* outBin, uint32_t* outRank,
                                             uint32_t K) {
  int tid = threadIdx.x;
  int base = tid * 16;
  uint32_t csum = 0;
#pragma unroll
  for (int k = 0; k < 16; k++) csum += hist[base + k];
  chunkSuf[tid] = csum;
  __syncthreads();
  if (tid < 64) {
    uint32_t cs[8];
    uint32_t g = 0;
#pragma unroll
    for (int m = 0; m < 8; m++) { cs[m] = chunkSuf[tid * 8 + m]; g += cs[m]; }
    uint32_t v = g;
#pragma unroll
    for (int off = 1; off < 64; off <<= 1) {
      uint32_t u = __shfl_down(v, off);
      if (tid + off < 64) v += u;
    }
    uint32_t run = v - g;
    for (int m = 7; m >= 0; m--) {
      chunkSuf[tid * 8 + m] = run;
      run += cs[m];
    }
  }
  __syncthreads();
  uint32_t run = chunkSuf[tid];
  for (int k = 15; k >= 0; k--) {
    uint32_t h = hist[base + k];
    if (run < K && run + h >= K) {
      *outBin = (uint32_t)(base + k);
      *outRank = K - run;
    }
    run += h;
  }
  __syncthreads();
}

// PASS 0: histogram of squared-mag bits >> 19.  PASS 1: compact matching bin.
// Thread layout: tid&127 = column group (4 cols), tid>>7 = row strip (128 rows).
// Row r+2 prefetched while computing row r; col+4 edge via shfl (lane63 scalar).
template <int PASS>
__device__ __forceinline__ void select_pass(const float* __restrict__ x,
                                            uint32_t* hist, uint32_t* cand,
                                            uint32_t* sCnt, uint32_t b0) {
  int tid = threadIdx.x;
  int wl = tid & 63;
  int lane_c = (tid & 127) << 2;
  int r0 = (tid >> 7) * 128;
  const bool haveE = lane_c + 4 < W;

  float4 vA, vB, vC;
  float eA = 0.f, eB = 0.f, eC = 0.f;
#define LDROW(r, v, e)                                        \
  {                                                           \
    if ((r) < H) {                                            \
      v = *(const float4*)(x + (r) * W + lane_c);             \
      if (wl == 63) e = haveE ? x[(r) * W + lane_c + 4] : 0.f;\
    } else { v = f4zero(); e = 0.f; }                         \
  }
  LDROW(r0, vA, eA)
  LDROW(r0 + 1, vB, eB)
  for (int it = 0; it < 128; ++it) {
    int r = r0 + it;
    if (it < 127) { LDROW(r + 2, vC, eC) } else { vC = f4zero(); eC = 0.f; }
    float ea = __shfl(vA.x, wl + 1); if (wl == 63) ea = eA;
    float eb = __shfl(vB.x, wl + 1); if (wl == 63) eb = eB;
    float a[5] = {vA.x, vA.y, vA.z, vA.w, ea};
    float bb[5] = {vB.x, vB.y, vB.z, vB.w, eb};
#pragma unroll
    for (int j = 0; j < 4; j++) {
      float g0 = a[j] - bb[j + 1];
      float g1 = a[j + 1] - bb[j];
      float msq = fmaf(g0, g0, fmaf(g1, g1, 1e-12f));
      uint32_t bits = __float_as_uint(msq);
      if (PASS == 0) {
        atomicAdd(&hist[bits >> 19], 1u);
      } else {
        if ((bits >> 19) == b0) {
          uint32_t idx = atomicAdd(sCnt, 1u);
          if (idx < CAND_CAP) cand[idx] = bits;
        }
      }
    }
    vA = vB; eA = eB; vB = vC; eB = eC;
  }
#undef LDROW
}

// One block per (tensor, image): exact rank-AX threshold (squared domain,
// sqrt-free) via radix select on float bits.
__global__ __launch_bounds__(512) void selectKernel(const float* __restrict__ target,
                                                    const float* __restrict__ pred,
                                                    float* __restrict__ thr) {
  __shared__ uint32_t hist[NB];        // 32 KB
  __shared__ uint32_t cand[CAND_CAP];  // 28 KB
  __shared__ uint32_t chunkSuf[512];   // 2 KB
  __shared__ uint32_t sBin, sRank, sCnt;
  int tid = threadIdx.x;
  int b = blockIdx.x;
  int img = b & 127;
  const float* __restrict__ x = ((b >> 7) ? pred : target) + (size_t)img * HW;

  for (int i = tid; i < NB; i += 512) hist[i] = 0;
  if (tid == 0) { sBin = 0; sRank = 1; sCnt = 0; }
  __syncthreads();

  select_pass<0>(x, hist, cand, &sCnt, 0);
  __syncthreads();
  block_select(hist, chunkSuf, &sBin, &sRank, AX);
  uint32_t b0 = sBin;
  uint32_t K1 = sRank;
  __syncthreads();

  select_pass<1>(x, hist, cand, &sCnt, b0);
  __syncthreads();
  uint32_t cnt = sCnt;
  if (cnt > CAND_CAP) cnt = CAND_CAP;  // expected ~3.3K; cap far in the tail

  // Mini-round 1: next 13 bits, in-LDS
  for (int i = tid; i < NB; i += 512) hist[i] = 0;
  __syncthreads();
  for (uint32_t j = tid; j < cnt; j += 512)
    atomicAdd(&hist[(cand[j] >> 6) & 0x1FFFu], 1u);
  __syncthreads();
  block_select(hist, chunkSuf, &sBin, &sRank, K1);
  uint32_t b1 = sBin;
  uint32_t K2 = sRank;
  __syncthreads();

  // Mini-round 2: last 6 bits
  for (int i = tid; i < NB; i += 512) hist[i] = 0;
  __syncthreads();
  for (uint32_t j = tid; j < cnt; j += 512) {
    uint32_t bits = cand[j];
    if (((bits >> 6) & 0x1FFFu) == b1) atomicAdd(&hist[bits & 63u], 1u);
  }
  __syncthreads();
  block_select(hist, chunkSuf, &sBin, &sRank, K2);
  if (tid == 0) {
    uint32_t tb = (b0 << 19) | (b1 << 6) | sBin;
    thr[b] = __uint_as_float(tb);  // SQUARED threshold bits
  }
}

// Per-position sequential carry over images. Thread = 4 cols x 1 row (float4);
// depth-2 image pipeline; col+4 edge via shfl (lane63 scalar loads).
// Block = 256 thr = 2 rows; XCD swizzle groups 64 contiguous rows per XCD.
__global__ __launch_bounds__(256) void scanKernel(const float* __restrict__ target,
                                                  const float* __restrict__ pred,
                                                  const float* __restrict__ thr,
                                                  double* __restrict__ sum) {
  __shared__ float sT[NIMG], sP[NIMG];
  int tid = threadIdx.x;
  if (tid < NIMG) { sT[tid] = thr[tid]; sP[tid] = thr[NIMG + tid]; }
  __syncthreads();
  int b = blockIdx.x;
  int rp = ((b & 7) << 5) + (b >> 3);  // XCD-contiguous row pairs
  int r = rp * 2 + (tid >> 7);
  int wl = tid & 63;
  int c = (tid & 127) << 2;
  const bool haveE = c + 4 < W;
  const bool haveB = r + 1 < H;
  size_t offA = (size_t)r * W + c;
  size_t offB = offA + W;

  float4 tA[2], tB[2], pA[2], pB[2];
  float eTa[2], eTb[2], ePa[2], ePb[2];

#define LOADI(i, buf)                                                 \
  {                                                                   \
    const float* xt = target + (size_t)(i) * HW;                      \
    const float* xp = pred + (size_t)(i) * HW;                        \
    tA[buf] = *(const float4*)(xt + offA);                            \
    pA[buf] = *(const float4*)(xp + offA);                            \
    tB[buf] = haveB ? *(const float4*)(xt + offB) : f4zero();         \
    pB[buf] = haveB ? *(const float4*)(xp + offB) : f4zero();         \
    eTa[buf] = 0.f; eTb[buf] = 0.f; ePa[buf] = 0.f; ePb[buf] = 0.f;   \
    if (wl == 63) {                                                   \
      eTa[buf] = haveE ? xt[offA + 4] : 0.f;                          \
      ePa[buf] = haveE ? xp[offA + 4] : 0.f;                          \
      eTb[buf] = (haveE && haveB) ? xt[offB + 4] : 0.f;               \
      ePb[buf] = (haveE && haveB) ? xp[offB + 4] : 0.f;               \
    }                                                                 \
  }

  float etf[4] = {0.f, 0.f, 0.f, 0.f}, epf[4] = {0.f, 0.f, 0.f, 0.f};
  float acc = 0.f;
  LOADI(0, 0)
#pragma unroll 2
  for (int i = 0; i < NIMG; ++i) {
    int cb = i & 1;
    if (i + 1 < NIMG) LOADI(i + 1, cb ^ 1)
    float tsqT = sT[i], tsqP = sP[i];
    float ea = __shfl(tA[cb].x, wl + 1); if (wl == 63) ea = eTa[cb];
    float eb = __shfl(tB[cb].x, wl + 1); if (wl == 63) eb = eTb[cb];
    float fa = __shfl(pA[cb].x, wl + 1); if (wl == 63) fa = ePa[cb];
    float fb = __shfl(pB[cb].x, wl + 1); if (wl == 63) fb = ePb[cb];
    float A[5] = {tA[cb].x, tA[cb].y, tA[cb].z, tA[cb].w, ea};
    float Bv[5] = {tB[cb].x, tB[cb].y, tB[cb].z, tB[cb].w, eb};
    float Pa[5] = {pA[cb].x, pA[cb].y, pA[cb].z, pA[cb].w, fa};
    float Pb[5] = {pB[cb].x, pB[cb].y, pB[cb].z, pB[cb].w, fb};
#pragma unroll
    for (int j = 0; j < 4; j++) {
      float g0 = A[j] - Bv[j + 1];
      float g1 = A[j + 1] - Bv[j];
      float msq = fmaf(g0, g0, fmaf(g1, g1, 1e-12f));
      if (msq >= tsqT) etf[j] = sqrtf(msq);
      g0 = Pa[j] - Pb[j + 1];
      g1 = Pa[j + 1] - Pb[j];
      float msp = fmaf(g0, g0, fmaf(g1, g1, 1e-12f));
      if (msp >= tsqP) epf[j] = sqrtf(msp);
      acc += fabsf((etf[j] - epf[j]) / (etf[j] + epf[j] + 1e-5f));
    }
  }
#undef LOADI

  for (int off = 32; off; off >>= 1) acc += __shfl_down(acc, off);
  __shared__ float ws4[4];
  if ((tid & 63) == 0) ws4[tid >> 6] = acc;
  __syncthreads();
  if (tid == 0) {
    double s = (double)ws4[0] + (double)ws4[1] + (double)ws4[2] + (double)ws4[3];
    atomicAdd(sum, s);
  }
}

__global__ void initKernel(double* __restrict__ sum) { *sum = 0.0; }

__global__ void finalKernel(const double* __restrict__ sum,
                            const float* __restrict__ alpha,
                            float* __restrict__ out) {
  out[0] = (float)((double)alpha[0] * (sum[0] / (double)((double)NIMG * (double)HW)));
}

extern "C" void kernel_launch(void* const* d_in, const int* in_sizes, int n_in,
                              void* d_out, int out_size, void* d_ws, size_t ws_size,
                              hipStream_t stream) {
  const float* pred = (const float*)d_in[0];    // predictions [16,8,512,512]
  const float* target = (const float*)d_in[1];  // target      [16,8,512,512]
  const float* alpha = (const float*)d_in[2];   // scalar
  // d_in[3] = Roberts kernels (fixed values, hardcoded)

  double* d_sum = (double*)d_ws;
  float* d_thr = (float*)((char*)d_ws + 64);  // 256 floats (squared-threshold bits)

  initKernel<<<1, 1, 0, stream>>>(d_sum);
  selectKernel<<<256, 512, 0, stream>>>(target, pred, d_thr);
  scanKernel<<<256, 256, 0, stream>>>(target, pred, d_thr, d_sum);
  finalKernel<<<1, 1, 0, stream>>>(d_sum, alpha, (float*)d_out);
}